// Round 2
// 285.095 us; speedup vs baseline: 1.0100x; 1.0100x over previous
//
#include <hip/hip_runtime.h>
#include <math.h>
#include <stdint.h>

#define NND 20000
#define DIMK 512
#define NE  320000

typedef __attribute__((ext_vector_type(8))) short short8;
typedef __attribute__((ext_vector_type(4))) float floatx4;

__device__ inline float bf2f(unsigned short h) {
    unsigned int u = ((unsigned int)h) << 16;
    return __uint_as_float(u);
}
__device__ inline unsigned short f2bf(float f) {
    unsigned int u = __float_as_uint(f);
    unsigned int r = (u + 0x7fffu + ((u >> 16) & 1u)) >> 16;
    return (unsigned short)r;
}

__device__ __forceinline__ void gld_lds16(const unsigned short* g, unsigned short* l) {
    __builtin_amdgcn_global_load_lds(
        (const __attribute__((address_space(1))) void*)g,
        (__attribute__((address_space(3))) void*)l,
        16, 0, 0);
}

// ---------------- fused pre-pass ----------------------------------------------
// Algebraic restructure: softmax(score) is invariant to dst-only shifts, so
//   score = qh[dst]·t[src],  qh = t@(scale·WqT Wk) + scale·bq@Wk
// and  out = (Σα t_s)@(Wo Wv)^T + (Wo bv + bo).
// The gather operand is t itself in bf16 (no fp8 anywhere -> numeric margin).
// blocks: [0,5000) logmap -> t bf16; [5000,5256) WoB cvt; [5256,5448) transposes
// (WqTs scaled); [5448,5450) bh; [5450,5578) bpr; [5578,6828) dst histogram
__global__ __launch_bounds__(256) void k_pre(const float* __restrict__ x,
                                             const float* __restrict__ Wq,
                                             const float* __restrict__ Wk,
                                             const float* __restrict__ Wv,
                                             const float* __restrict__ Wo,
                                             const float* __restrict__ bq,
                                             const float* __restrict__ bv,
                                             const float* __restrict__ bo,
                                             const int* __restrict__ dst,
                                             int* __restrict__ counts,
                                             unsigned short* __restrict__ t,
                                             unsigned short* __restrict__ WqTs,
                                             unsigned short* __restrict__ WkT,
                                             unsigned short* __restrict__ WvT,
                                             unsigned short* __restrict__ WoB,
                                             float* __restrict__ bh,
                                             float* __restrict__ bpr,
                                             float scf) {
    int blk = blockIdx.x, tid = threadIdx.x;
    if (blk < 5000) {
        int row = blk * 4 + (tid >> 6);
        int lane = tid & 63;
        const floatx4* xp = (const floatx4*)(x + (size_t)row * DIMK + lane * 8);
        floatx4 x0 = xp[0], x1 = xp[1];
        float ss = 0.f;
#pragma unroll
        for (int i = 0; i < 4; i++) { ss += x0[i] * x0[i]; ss += x1[i] * x1[i]; }
#pragma unroll
        for (int off = 32; off >= 1; off >>= 1) ss += __shfl_xor(ss, off, 64);
        float n  = sqrtf(ss);
        float nc = fminf(fmaxf(n, 1e-7f), 1.0f - 1e-6f);
        float fac = atanhf(nc) / nc;
        union { short8 v; unsigned short u[8]; } o;
#pragma unroll
        for (int i = 0; i < 4; i++) { o.u[i] = f2bf(fac * x0[i]); o.u[4 + i] = f2bf(fac * x1[i]); }
        *(short8*)(t + (size_t)row * DIMK + lane * 8) = o.v;
    } else if (blk < 5256) {
        int i = (blk - 5000) * 256 + tid;           // 0..65535, 4 elems each
        floatx4 f = *(const floatx4*)(Wo + (size_t)i * 4);
        union { unsigned long long d; unsigned short u[4]; } o;
#pragma unroll
        for (int q = 0; q < 4; q++) o.u[q] = f2bf(f[q]);
        *(unsigned long long*)(WoB + (size_t)i * 4) = o.d;
    } else if (blk < 5448) {
        // LDS-tiled 64x64 transpose: WqTs = Wq^T * scf, WkT = Wk^T, WvT = Wv^T
        int g = blk - 5256;                          // 0..191
        int m = g >> 6, tile = g & 63;
        int tr = tile >> 3, tc = tile & 7;
        const float* srcm = (m == 0) ? Wq : (m == 1) ? Wk : Wv;
        unsigned short* dstp = (m == 0) ? WqTs : (m == 1) ? WkT : WvT;
        float sc = (m == 0) ? scf : 1.0f;
        __shared__ float tl[64][65];
#pragma unroll
        for (int i = 0; i < 16; i++) {
            int idx = i * 256 + tid; int r = idx >> 6, c = idx & 63;
            tl[c][r] = srcm[(size_t)(tr * 64 + r) * 512 + tc * 64 + c];
        }
        __syncthreads();
#pragma unroll
        for (int i = 0; i < 16; i++) {
            int idx = i * 256 + tid; int r = idx >> 6, c = idx & 63;
            dstp[(size_t)(tc * 64 + r) * 512 + tr * 64 + c] = f2bf(tl[r][c] * sc);
        }
    } else if (blk < 5450) {
        int col = (blk - 5448) * 256 + tid;          // 0..511
        float s = 0.f;
#pragma unroll 8
        for (int m = 0; m < 512; m++) s += bq[m] * Wk[(size_t)m * 512 + col];
        bh[col] = s * scf;
    } else if (blk < 5578) {
        int row = (blk - 5450) * 4 + (tid >> 6);     // 0..511
        int lane = tid & 63;
        const floatx4* wp = (const floatx4*)(Wo + (size_t)row * 512 + lane * 8);
        const floatx4* bp = (const floatx4*)(bv + lane * 8);
        floatx4 a0 = wp[0], a1 = wp[1], c0 = bp[0], c1 = bp[1];
        float s = 0.f;
#pragma unroll
        for (int i = 0; i < 4; i++) { s += a0[i] * c0[i]; s += a1[i] * c1[i]; }
#pragma unroll
        for (int off = 32; off >= 1; off >>= 1) s += __shfl_xor(s, off, 64);
        if (lane == 0) bpr[row] = s + bo[row];
    } else {
        int e = (blk - 5578) * 256 + tid;
        if (e < NE) atomicAdd(&counts[dst[e]], 1);
    }
}

// ---------------- double-buffered GEMM, 128x128, BK=32, XCD swizzle -----------
// q-mode (out_f==0, NT=4): bf16 out to out_q. proj mode (out_f!=0): fp32 out.
__global__ __launch_bounds__(256) void k_gemm(const unsigned short* __restrict__ A,
                                              const unsigned short* __restrict__ B,
                                              const float* __restrict__ biasf,
                                              unsigned short* __restrict__ out_q,
                                              float* __restrict__ out_f,
                                              int M, int MT, int NT, int Ncols) {
    __shared__ unsigned short smem[16384];
    int b = blockIdx.x;
    int xcd = b & 7, i = b >> 3;
    int nt = i % NT, mt = (i / NT) * 8 + xcd;
    if (mt >= MT) return;
    int m0 = mt * 128, n0 = nt * 128;
    int tid = threadIdx.x, wv = tid >> 6, ln = tid & 63;
    int lr = ln & 15, qd = ln >> 4;
    int mh = wv >> 1, nh = wv & 1;

    floatx4 acc[4][4] = {};
    int srow = wv * 16 + (ln >> 2);
    int scol = (((ln & 3) ^ (ln >> 4)) & 3) * 8;
    int fsw = (qd ^ (lr >> 2)) & 3;

    {
        unsigned short* Ab = smem;
        unsigned short* Bb = smem + 8192;
#pragma unroll
        for (int p = 0; p < 2; p++) {
            int tr = p * 64 + srow;
            int ar = m0 + tr; if (ar > M - 1) ar = M - 1;
            gld_lds16(A + (size_t)ar * DIMK + scol, Ab + (p * 64 + wv * 16) * 32);
            gld_lds16(B + (size_t)(n0 + tr) * DIMK + scol, Bb + (p * 64 + wv * 16) * 32);
        }
    }

    for (int it = 0; it < 16; it++) {
        int cur = it & 1, nxt = cur ^ 1;
        __syncthreads();
        if (it + 1 < 16) {
            int kb = (it + 1) * 32;
            unsigned short* Ab = smem + nxt * 4096;
            unsigned short* Bb = smem + 8192 + nxt * 4096;
#pragma unroll
            for (int p = 0; p < 2; p++) {
                int tr = p * 64 + srow;
                int ar = m0 + tr; if (ar > M - 1) ar = M - 1;
                gld_lds16(A + (size_t)ar * DIMK + kb + scol, Ab + (p * 64 + wv * 16) * 32);
                gld_lds16(B + (size_t)(n0 + tr) * DIMK + kb + scol, Bb + (p * 64 + wv * 16) * 32);
            }
        }
        const unsigned short* Ac = smem + cur * 4096;
        const unsigned short* Bc = smem + 8192 + cur * 4096;
        short8 af[4], bfr[4];
#pragma unroll
        for (int mi = 0; mi < 4; mi++)
            af[mi] = *(const short8*)(Ac + (mh * 64 + mi * 16 + lr) * 32 + fsw * 8);
#pragma unroll
        for (int ni = 0; ni < 4; ni++)
            bfr[ni] = *(const short8*)(Bc + (nh * 64 + ni * 16 + lr) * 32 + fsw * 8);
#pragma unroll
        for (int mi = 0; mi < 4; mi++)
#pragma unroll
            for (int ni = 0; ni < 4; ni++)
                acc[mi][ni] = __builtin_amdgcn_mfma_f32_16x16x32_bf16(af[mi], bfr[ni], acc[mi][ni], 0, 0, 0);
    }

    float bb[4];
#pragma unroll
    for (int ni = 0; ni < 4; ni++) bb[ni] = biasf[n0 + nh * 64 + ni * 16 + lr];

    if (!out_f) {
        int col0 = nt * 128;
        unsigned short* cs = smem;
#pragma unroll
        for (int g = 0; g < 4; g++) {
            __syncthreads();
            if (mh == (g >> 1)) {
                int miB = (g & 1) * 2;
#pragma unroll
                for (int m2 = 0; m2 < 2; m2++) {
                    int mi = miB + m2;
                    int lrow = mi * 16 + qd * 4 - (g & 1) * 32;
#pragma unroll
                    for (int ni = 0; ni < 4; ni++) {
                        int col = nh * 64 + ni * 16 + lr;
#pragma unroll
                        for (int r = 0; r < 4; r++)
                            cs[(lrow + r) * 128 + col] = f2bf(acc[mi][ni][r] + bb[ni]);
                    }
                }
            }
            __syncthreads();
#pragma unroll
            for (int itr = 0; itr < 2; itr++) {
                int slot = itr * 256 + tid;
                int row = slot >> 4, cg = slot & 15;
                int gm = m0 + g * 32 + row;
                if (gm < M) {
                    short8 vv = *(const short8*)(cs + row * 128 + cg * 8);
                    *(short8*)(out_q + (size_t)gm * 512 + col0 + cg * 8) = vv;
                }
            }
        }
    } else {
#pragma unroll
        for (int ni = 0; ni < 4; ni++) {
            int gn = n0 + nh * 64 + ni * 16 + lr;
#pragma unroll
            for (int mi = 0; mi < 4; mi++) {
                int gm0 = m0 + mh * 64 + mi * 16 + qd * 4;
#pragma unroll
                for (int r = 0; r < 4; r++) {
                    int gm = gm0 + r;
                    if (gm < M) out_f[(size_t)gm * Ncols + gn] = acc[mi][ni][r] + bb[ni];
                }
            }
        }
    }
}

// ---------------- CSR scan ----------------------------------------------------
__global__ __launch_bounds__(1024) void k_scan(const int* __restrict__ counts,
                                               int* __restrict__ offsets,
                                               int* __restrict__ pos) {
    const int C = 20;
    __shared__ int wsum[16];
    __shared__ int wpre[16];
    int tid = threadIdx.x, lane = tid & 63, w = tid >> 6;
    int local[C];
    int run = 0;
#pragma unroll
    for (int i = 0; i < C; i++) {
        int idx = tid * C + i;
        int c = (idx < NND) ? counts[idx] : 0;
        local[i] = run; run += c;
    }
    int v = run;
#pragma unroll
    for (int off = 1; off < 64; off <<= 1) {
        int u = __shfl_up(v, off, 64);
        if (lane >= off) v += u;
    }
    if (lane == 63) wsum[w] = v;
    __syncthreads();
    if (tid == 0) { int acc = 0; for (int i = 0; i < 16; i++) { wpre[i] = acc; acc += wsum[i]; } }
    __syncthreads();
    int texcl = wpre[w] + (v - run);
#pragma unroll
    for (int i = 0; i < C; i++) {
        int idx = tid * C + i;
        if (idx < NND) { int o = texcl + local[i]; offsets[idx] = o; pos[idx] = o; }
    }
    if (tid == 1023) offsets[NND] = texcl + run;
}

// ---------------- scatter + the two 512^3 weight-products (hidden) ------------
// blocks [0,1250): edge scatter; [1250,1282): prod0 Amat = scf*Wq^T Wk layout
// Amat[n,c] = scf*sum_m Wq[m,c]Wk[m,n]; prod1 Wovb = Wo@Wv.
__global__ __launch_bounds__(256) void k_scatter(const int* __restrict__ dst,
                                                 const int* __restrict__ src,
                                                 int* __restrict__ pos,
                                                 int* __restrict__ ssrc,
                                                 const unsigned short* __restrict__ WkT,
                                                 const unsigned short* __restrict__ WqTs,
                                                 const unsigned short* __restrict__ WoB,
                                                 const unsigned short* __restrict__ WvT,
                                                 unsigned short* __restrict__ Amat,
                                                 unsigned short* __restrict__ Wovb) {
    __shared__ unsigned short smem[16384];
    int b = blockIdx.x;
    if (b < 1250) {
        int e = b * 256 + threadIdx.x;
        if (e < NE) { int p = atomicAdd(&pos[dst[e]], 1); ssrc[p] = src[e]; }
        return;
    }
    int g = b - 1250;                   // 0..31
    int prod = g >> 4;
    int mt = (g >> 2) & 3, nt = g & 3;
    const unsigned short* A = prod ? WoB : WkT;
    const unsigned short* B = prod ? WvT : WqTs;
    unsigned short* outp = prod ? Wovb : Amat;
    int m0 = mt * 128, n0 = nt * 128;
    int tid = threadIdx.x, wv = tid >> 6, ln = tid & 63;
    int lr = ln & 15, qd = ln >> 4;
    int mh = wv >> 1, nh = wv & 1;
    floatx4 acc[4][4] = {};
    int srow = wv * 16 + (ln >> 2);
    int scol = (((ln & 3) ^ (ln >> 4)) & 3) * 8;
    int fsw = (qd ^ (lr >> 2)) & 3;
    {
        unsigned short* Ab = smem;
        unsigned short* Bb = smem + 8192;
#pragma unroll
        for (int p = 0; p < 2; p++) {
            int tr = p * 64 + srow;
            gld_lds16(A + (size_t)(m0 + tr) * DIMK + scol, Ab + (p * 64 + wv * 16) * 32);
            gld_lds16(B + (size_t)(n0 + tr) * DIMK + scol, Bb + (p * 64 + wv * 16) * 32);
        }
    }
    for (int it = 0; it < 16; it++) {
        int cur = it & 1, nxt = cur ^ 1;
        __syncthreads();
        if (it + 1 < 16) {
            int kb = (it + 1) * 32;
            unsigned short* Ab = smem + nxt * 4096;
            unsigned short* Bb = smem + 8192 + nxt * 4096;
#pragma unroll
            for (int p = 0; p < 2; p++) {
                int tr = p * 64 + srow;
                gld_lds16(A + (size_t)(m0 + tr) * DIMK + kb + scol, Ab + (p * 64 + wv * 16) * 32);
                gld_lds16(B + (size_t)(n0 + tr) * DIMK + kb + scol, Bb + (p * 64 + wv * 16) * 32);
            }
        }
        const unsigned short* Ac = smem + cur * 4096;
        const unsigned short* Bc = smem + 8192 + cur * 4096;
        short8 af[4], bfr[4];
#pragma unroll
        for (int mi = 0; mi < 4; mi++)
            af[mi] = *(const short8*)(Ac + (mh * 64 + mi * 16 + lr) * 32 + fsw * 8);
#pragma unroll
        for (int ni = 0; ni < 4; ni++)
            bfr[ni] = *(const short8*)(Bc + (nh * 64 + ni * 16 + lr) * 32 + fsw * 8);
#pragma unroll
        for (int mi = 0; mi < 4; mi++)
#pragma unroll
            for (int ni = 0; ni < 4; ni++)
                acc[mi][ni] = __builtin_amdgcn_mfma_f32_16x16x32_bf16(af[mi], bfr[ni], acc[mi][ni], 0, 0, 0);
    }
#pragma unroll
    for (int ni = 0; ni < 4; ni++) {
        int gn = n0 + nh * 64 + ni * 16 + lr;
#pragma unroll
        for (int mi = 0; mi < 4; mi++) {
            int gm0 = m0 + mh * 64 + mi * 16 + qd * 4;
#pragma unroll
            for (int r = 0; r < 4; r++)
                outp[(size_t)(gm0 + r) * 512 + gn] = f2bf(acc[mi][ni][r]);
        }
    }
}

// ---------------- fused score+softmax+aggregate -------------------------------
// qh: bf16 [N,512] (carries scale); t: bf16 [N,512].
// ONE bf16 row load per edge serves both the score dot and the aggregation.
__global__ __launch_bounds__(256) void k_fsa(const int* __restrict__ offsets,
                                             const int* __restrict__ ssrc,
                                             const unsigned short* __restrict__ qb,
                                             const unsigned short* __restrict__ tb,
                                             unsigned short* __restrict__ attn) {
    __shared__ float sacc[4][512];
    __shared__ float sden[4];
    int n = blockIdx.x, tid = threadIdx.x, wv = tid >> 6, ln = tid & 63;
    int beg = offsets[n], end = offsets[n + 1];
    union { short8 v; unsigned short u[8]; } qu;
    qu.v = *(const short8*)(qb + (size_t)n * 512 + ln * 8);
    float qf[8];
#pragma unroll
    for (int j = 0; j < 8; j++) qf[j] = bf2f(qu.u[j]);
    float av[8] = {0, 0, 0, 0, 0, 0, 0, 0};
    float den = 0.f;
    int i = beg + wv * 2;
    for (; i + 1 < end; i += 8) {
        const unsigned short* p0 = tb + (size_t)ssrc[i] * 512 + ln * 8;
        const unsigned short* p1 = tb + (size_t)ssrc[i + 1] * 512 + ln * 8;
        union { short8 v; unsigned short u[8]; } r0, r1;
        r0.v = *(const short8*)p0;
        r1.v = *(const short8*)p1;
        float t0[8], t1[8];
        float d0 = 0.f, d1 = 0.f;
#pragma unroll
        for (int j = 0; j < 8; j++) {
            t0[j] = bf2f(r0.u[j]); d0 += qf[j] * t0[j];
            t1[j] = bf2f(r1.u[j]); d1 += qf[j] * t1[j];
        }
#pragma unroll
        for (int off = 32; off >= 1; off >>= 1) {
            d0 += __shfl_xor(d0, off, 64);
            d1 += __shfl_xor(d1, off, 64);
        }
        float w0 = __expf(d0), w1 = __expf(d1);
        den += w0 + w1;
#pragma unroll
        for (int j = 0; j < 8; j++) av[j] += w0 * t0[j] + w1 * t1[j];
    }
    if (i < end) {
        const unsigned short* p0 = tb + (size_t)ssrc[i] * 512 + ln * 8;
        union { short8 v; unsigned short u[8]; } r0;
        r0.v = *(const short8*)p0;
        float t0[8];
        float d0 = 0.f;
#pragma unroll
        for (int j = 0; j < 8; j++) { t0[j] = bf2f(r0.u[j]); d0 += qf[j] * t0[j]; }
#pragma unroll
        for (int off = 32; off >= 1; off >>= 1) d0 += __shfl_xor(d0, off, 64);
        float w0 = __expf(d0);
        den += w0;
#pragma unroll
        for (int j = 0; j < 8; j++) av[j] += w0 * t0[j];
    }
    floatx4 s0v = {av[0], av[1], av[2], av[3]};
    floatx4 s1v = {av[4], av[5], av[6], av[7]};
    *(floatx4*)&sacc[wv][ln * 8]     = s0v;
    *(floatx4*)&sacc[wv][ln * 8 + 4] = s1v;
    if (ln == 0) sden[wv] = den;
    __syncthreads();
    float inv = 1.0f / (sden[0] + sden[1] + sden[2] + sden[3]);
    int c = tid * 2;
    float t0 = sacc[0][c] + sacc[1][c] + sacc[2][c] + sacc[3][c];
    float t1 = sacc[0][c + 1] + sacc[1][c + 1] + sacc[2][c + 1] + sacc[3][c + 1];
    attn[(size_t)n * 512 + c]     = f2bf(t0 * inv);
    attn[(size_t)n * 512 + c + 1] = f2bf(t1 * inv);
}

// ---------------- expmap0 in place --------------------------------------------
__global__ __launch_bounds__(64) void k_expmap(float* h) {
    int row = blockIdx.x, lane = threadIdx.x;
    floatx4* hp = (floatx4*)(h + (size_t)row * DIMK + lane * 8);
    floatx4 h0 = hp[0], h1 = hp[1];
    float ss = 0.f;
#pragma unroll
    for (int i = 0; i < 4; i++) { ss += h0[i] * h0[i]; ss += h1[i] * h1[i]; }
#pragma unroll
    for (int off = 32; off >= 1; off >>= 1) ss += __shfl_xor(ss, off, 64);
    float n  = sqrtf(ss);
    float nc = fmaxf(n, 1e-7f);
    float fac = tanhf(nc) / nc;
#pragma unroll
    for (int i = 0; i < 4; i++) { h0[i] *= fac; h1[i] *= fac; }
    hp[0] = h0; hp[1] = h1;
}

extern "C" void kernel_launch(void* const* d_in, const int* in_sizes, int n_in,
                              void* d_out, int out_size, void* d_ws, size_t ws_size,
                              hipStream_t stream) {
    const float* x  = (const float*)d_in[0];
    const int* src  = (const int*)d_in[1];
    const int* dst  = (const int*)d_in[2];
    const float* Wq = (const float*)d_in[3];
    const float* bq = (const float*)d_in[4];
    const float* Wk = (const float*)d_in[5];
    const float* Wv = (const float*)d_in[7];
    const float* bv = (const float*)d_in[8];
    const float* Wo = (const float*)d_in[9];
    const float* bo = (const float*)d_in[10];
    float* out = (float*)d_out;

    char* ws = (char*)d_ws;
    const size_t RB  = (size_t)NND * DIMK * 2;     // 20.48 MB bf16 [N,512]
    const size_t WB  = (size_t)DIMK * DIMK * 2;    // 512 KB bf16 [512,512]
    unsigned short* t    = (unsigned short*)(ws);
    unsigned short* qh   = (unsigned short*)(ws + RB);      // attn aliases qh
    unsigned short* WqTs = (unsigned short*)(ws + 2 * RB);
    unsigned short* WkT  = (unsigned short*)(ws + 2 * RB + WB);
    unsigned short* WvT  = (unsigned short*)(ws + 2 * RB + 2 * WB);
    unsigned short* WoB  = (unsigned short*)(ws + 2 * RB + 3 * WB);
    unsigned short* Amat = (unsigned short*)(ws + 2 * RB + 4 * WB);
    unsigned short* Wovb = (unsigned short*)(ws + 2 * RB + 5 * WB);
    float* bh            = (float*)(ws + 2 * RB + 6 * WB);
    float* bpr           = (float*)(ws + 2 * RB + 6 * WB + 2048);
    char* p = ws + 2 * RB + 6 * WB + 4096;
    int* ssrc    = (int*)p;
    int* counts  = ssrc + NE;
    int* offsets = counts + NND;
    int* pos     = offsets + NND + 2;
    unsigned short* attn = qh;   // safe alias: block n reads only qh row n first

    hipMemsetAsync(counts, 0, (size_t)NND * 4, stream);

    const float scf = 0.04419417382415922f;        // 1/sqrt(512)
    k_pre<<<6828, 256, 0, stream>>>(x, Wq, Wk, Wv, Wo, bq, bv, bo, dst, counts,
                                    t, WqTs, WkT, WvT, WoB, bh, bpr, scf);

    k_scan<<<1, 1024, 0, stream>>>(counts, offsets, pos);
    // scatter + the two 512^3 weight-products in one launch
    k_scatter<<<1282, 256, 0, stream>>>(dst, src, pos, ssrc,
                                        WkT, WqTs, WoB, WvT, Amat, Wovb);

    // qh = t @ Amat^T + bh  (bf16 out)
    k_gemm<<<8 * 20 * 4, 256, 0, stream>>>(t, Amat, bh, qh, nullptr,
                                           NND, 157, 4, 512);

    k_fsa<<<NND, 256, 0, stream>>>(offsets, ssrc, qh, t, attn);

    // out = attn @ Wovb^T + bpr (fp32), expmap in place
    k_gemm<<<8 * 20 * 4, 256, 0, stream>>>(attn, Wovb, bpr, nullptr, out,
                                           NND, 157, 4, 512);
    k_expmap<<<NND, 64, 0, stream>>>(out);
}